// Round 7
// baseline (305.023 us; speedup 1.0000x reference)
//
#include <hip/hip_runtime.h>
#include <cstdint>
#include <cstddef>

typedef unsigned short u16;
typedef unsigned int u32;
typedef short bf16x8 __attribute__((ext_vector_type(8)));
typedef float floatx4 __attribute__((ext_vector_type(4)));

#define GLD16(gp, sp) __builtin_amdgcn_global_load_lds(                      \
    (const __attribute__((address_space(1))) void*)(gp),                     \
    (__attribute__((address_space(3))) void*)(sp), 16, 0, 0)

__device__ __forceinline__ u16 f2bf(float f) {
  unsigned u = __float_as_uint(f);
  u += 0x7fffu + ((u >> 16) & 1u);   // round-to-nearest-even
  return (u16)(u >> 16);
}

// ---------------- prep: x cvt + router ----------------
// regions: [0,1024) cvt_x | [1024,1536) router+scatter
__global__ __launch_bounds__(256) void prep_kernel(
    const float* __restrict__ x, const float* __restrict__ rw, const float* __restrict__ rbias,
    u16* __restrict__ xb, float* __restrict__ ew,
    int* __restrict__ row_token, float* __restrict__ row_scale, int* __restrict__ cnt) {
  const int b = blockIdx.x, tid = threadIdx.x;
  if (b < 1024) {                       // ---- x f32 -> bf16
    const float4* in4 = (const float4*)x;
    ushort4* out4 = (ushort4*)xb;
    int i = (b << 8) + tid;
#pragma unroll
    for (int rep = 0; rep < 2; ++rep, i += 262144) {
      float4 v = in4[i];
      ushort4 o;
      o.x = f2bf(v.x); o.y = f2bf(v.y); o.z = f2bf(v.z); o.w = f2bf(v.w);
      out4[i] = o;
    }
  } else {                              // ---- router (4 tokens/block) + direct scatter
    const int wave = tid >> 6, lane = tid & 63;
    const int t = ((b - 1024) << 2) + wave;
    const float4* xv = (const float4*)(x + (size_t)t * 1024);
    float acc[8];
#pragma unroll
    for (int e = 0; e < 8; ++e) acc[e] = 0.f;
    for (int j = lane; j < 256; j += 64) {
      float4 xx = xv[j];
#pragma unroll
      for (int e = 0; e < 8; ++e) {
        float4 wv = ((const float4*)(rw + (size_t)e * 1024))[j];
        acc[e] += xx.x * wv.x + xx.y * wv.y + xx.z * wv.z + xx.w * wv.w;
      }
    }
#pragma unroll
    for (int e = 0; e < 8; ++e) {
      float v = acc[e];
#pragma unroll
      for (int off = 32; off > 0; off >>= 1) v += __shfl_down(v, off);
      acc[e] = v;
    }
    if (lane == 0) {
      float p[8];
      float mx = -1e30f;
#pragma unroll
      for (int e = 0; e < 8; ++e) { p[e] = acc[e] + rbias[e]; mx = fmaxf(mx, p[e]); }
      float sum = 0.f;
#pragma unroll
      for (int e = 0; e < 8; ++e) { p[e] = __expf(p[e] - mx); sum += p[e]; }
      float inv = 1.f / sum;
#pragma unroll
      for (int e = 0; e < 8; ++e) p[e] *= inv;
      int i0 = 0;
#pragma unroll
      for (int e = 1; e < 8; ++e) if (p[e] > p[i0]) i0 = e;
      int i1 = (i0 == 0) ? 1 : 0;
#pragma unroll
      for (int e = 0; e < 8; ++e) if (e != i0 && e != i1 && p[e] > p[i1]) i1 = e;
      ew[t * 2 + 0] = p[i0];
      ew[t * 2 + 1] = p[i1];
      int s0 = atomicAdd(&cnt[i0], 1);           // fixed 2048-slot region per expert
      row_token[(i0 << 11) + s0] = t;
      row_scale[(i0 << 11) + s0] = p[i0];
      int s1 = atomicAdd(&cnt[i1], 1);
      row_token[(i1 << 11) + s1] = t;
      row_scale[(i1 << 11) + s1] = p[i1];
    }
  }
}

// B-stage: thread owns col n (idx&127) and k-quad q (idx>>7) of the 128x32 tile.
// load: 8 f32 rows, stride C (coalesced 256B across lanes).
__device__ __forceinline__ void load_b8(const float* __restrict__ src0, int C, int idx,
                                        float* __restrict__ f) {
  const int n = idx & 127, q = idx >> 7;
  const float* src = src0 + (size_t)(q * 8) * C + n;
#pragma unroll
  for (int j = 0; j < 8; ++j) f[j] = src[(size_t)j * C];
}
// write: cvt+pack -> single conflict-free ds_write_b128 into chunk-major bf16 layout.
__device__ __forceinline__ void write_b8(const float* __restrict__ f, int idx,
                                         u16* __restrict__ Bs) {
  const int n = idx & 127, q = idx >> 7;
  u32 pk[4];
#pragma unroll
  for (int m = 0; m < 4; ++m) pk[m] = (u32)f2bf(f[2 * m]) | ((u32)f2bf(f[2 * m + 1]) << 16);
  *(uint4*)(Bs + ((n >> 4) << 9) + (q << 7) + ((n & 15) << 3)) =
      make_uint4(pk[0], pk[1], pk[2], pk[3]);
}

// ---------------- GEMM1: 128x128, BK=32, double-buffered pipeline ----------------
// grid 2048: xcd=d&7, j=d>>3: colHi=j&1, rb=(j>>1)&15, e=j>>5; colIdx=xcd+8*colHi.
// One barrier/iter; prefetch (B-regs + A-GLD16) issued AFTER the barrier so the
// vmcnt(0) drain at the next barrier only sees loads issued a full iter earlier.
__global__ __launch_bounds__(256) void gemm1_act_kernel(
    const u16* __restrict__ xb, const float* __restrict__ w1,
    const float* __restrict__ w1b,
    const int* __restrict__ row_token, const float* __restrict__ row_scale,
    const int* __restrict__ cnt, u16* __restrict__ actS) {
  const int d = blockIdx.x;
  const int xcd = d & 7, j = d >> 3;
  const int colHi = j & 1, rb = (j >> 1) & 15, e = j >> 5;
  if (rb * 128 >= cnt[e]) return;
  const int colBase = (xcd + (colHi << 3)) << 7;
  const int slotB = (e << 11) + (rb << 7);
  __shared__ __align__(16) u16 As[2][4096];
  __shared__ __align__(16) u16 Bs[2][4096];
  const int tid = threadIdx.x, lane = tid & 63, wave = tid >> 6;
  const int row16 = lane & 15, chunk = lane >> 4;
  const float* w1e = w1 + (size_t)e * 2097152 + colBase;   // f32 (1024 k x 2048 n)
  int tk0 = row_token[slotB + wave * 16 + row16];       if (tk0 < 0) tk0 = 0;
  int tk1 = row_token[slotB + (wave + 4) * 16 + row16]; if (tk1 < 0) tk1 = 0;
  const u16* aP0 = xb + (size_t)tk0 * 1024 + chunk * 8;
  const u16* aP1 = xb + (size_t)tk1 * 1024 + chunk * 8;
  const int wr = wave >> 1, wc = wave & 1;
  floatx4 acc[4][4];
#pragma unroll
  for (int mi = 0; mi < 4; ++mi)
#pragma unroll
    for (int ni = 0; ni < 4; ++ni) acc[mi][ni] = floatx4{0.f, 0.f, 0.f, 0.f};

  float fb[16];
  // preamble: stage iter 0 into buffers[0]
  load_b8(w1e, 2048, tid, fb);
  load_b8(w1e, 2048, tid + 256, fb + 8);
  write_b8(fb, tid, Bs[0]);
  write_b8(fb + 8, tid + 256, Bs[0]);
  GLD16(aP0, As[0] + wave * 512);
  GLD16(aP1, As[0] + (wave + 4) * 512);

  for (int kt = 0; kt < 32; ++kt) {
    const int p = kt & 1;
    __syncthreads();   // drains prev-iter GLD16 + lgkm; buffers[p] now valid
    if (kt < 31) {     // issue prefetch for kt+1 into buffers[1-p]
      const float* wsrc = w1e + (size_t)(kt + 1) * 32 * 2048;
      load_b8(wsrc, 2048, tid, fb);
      load_b8(wsrc, 2048, tid + 256, fb + 8);
      const int k = (kt + 1) * 32;
      GLD16(aP0 + k, As[1 - p] + wave * 512);
      GLD16(aP1 + k, As[1 - p] + (wave + 4) * 512);
    }
    bf16x8 af[4], bfr[4];
#pragma unroll
    for (int mi = 0; mi < 4; ++mi)
      af[mi] = *(const bf16x8*)(As[p] + (wr * 4 + mi) * 512 + lane * 8);
#pragma unroll
    for (int ni = 0; ni < 4; ++ni)
      bfr[ni] = *(const bf16x8*)(Bs[p] + (wc * 4 + ni) * 512 + lane * 8);
#pragma unroll
    for (int mi = 0; mi < 4; ++mi)
#pragma unroll
      for (int ni = 0; ni < 4; ++ni)
        acc[mi][ni] = __builtin_amdgcn_mfma_f32_16x16x32_bf16(af[mi], bfr[ni], acc[mi][ni], 0, 0, 0);
    if (kt < 31) {     // cvt+pack after MFMA; waitcnt for fb lands here
      write_b8(fb, tid, Bs[1 - p]);
      write_b8(fb + 8, tid + 256, Bs[1 - p]);
    }
  }

  const int cl = lane & 15, ql = lane >> 4;
#pragma unroll
  for (int mi = 0; mi < 4; ++mi) {
#pragma unroll
    for (int r = 0; r < 4; ++r) {
      const int slot = slotB + wr * 64 + mi * 16 + ql * 4 + r;
      const float c = row_scale[slot];  // 0 for padded slots -> zero fill of actS
#pragma unroll
      for (int ni = 0; ni < 4; ++ni) {
        const int n = colBase + wc * 64 + ni * 16 + cl;  // interleaved col of w1
        float v = acc[mi][ni][r] + w1b[e * 2048 + n];
        float o = __shfl_xor(v, 1);  // partner column
        if ((lane & 1) == 0) {       // even lane = gate col
          float g = fminf(v, 7.f);
          float u = fminf(fmaxf(o, -7.f), 7.f);
          float sg = 1.f / (1.f + __expf(-1.702f * g));
          float a = (u + 1.f) * (g * sg);
          actS[(size_t)slot * 1024 + (n >> 1)] = f2bf(c * a);
        }
      }
    }
  }
}

// ---------------- GEMM2: 128x128, BK=32, split-K=2, double-buffered pipeline ----
// grid 2048: xcd=d&7 (colIdx over 8 tiles), j=d>>3: ks=j&1, rb=(j>>1)&15, e=j>>5.
__global__ __launch_bounds__(256) void gemm2_add_kernel(
    const u16* __restrict__ actS, const float* __restrict__ w2, const float* __restrict__ w2b,
    const int* __restrict__ row_token, const float* __restrict__ row_scale,
    const int* __restrict__ cnt, float* __restrict__ out) {
  const int d = blockIdx.x;
  const int xcd = d & 7, j = d >> 3;
  const int ks = j & 1, rb = (j >> 1) & 15, e = j >> 5;
  if (rb * 128 >= cnt[e]) return;
  const int colBase = xcd << 7;
  const int slotB = (e << 11) + (rb << 7);
  const int k0 = ks << 9;
  __shared__ __align__(16) u16 As[2][4096];
  __shared__ __align__(16) u16 Bs[2][4096];
  const int tid = threadIdx.x, lane = tid & 63, wave = tid >> 6;
  const int row16 = lane & 15, chunk = lane >> 4;
  const float* w2e = w2 + (size_t)e * 1048576 + (size_t)k0 * 1024 + colBase;  // f32
  const u16* aP0 = actS + (size_t)(slotB + wave * 16 + row16) * 1024 + k0 + chunk * 8;
  const u16* aP1 = actS + (size_t)(slotB + (wave + 4) * 16 + row16) * 1024 + k0 + chunk * 8;
  const int wr = wave >> 1, wc = wave & 1;
  floatx4 acc[4][4];
#pragma unroll
  for (int mi = 0; mi < 4; ++mi)
#pragma unroll
    for (int ni = 0; ni < 4; ++ni) acc[mi][ni] = floatx4{0.f, 0.f, 0.f, 0.f};

  float fb[16];
  load_b8(w2e, 1024, tid, fb);
  load_b8(w2e, 1024, tid + 256, fb + 8);
  write_b8(fb, tid, Bs[0]);
  write_b8(fb + 8, tid + 256, Bs[0]);
  GLD16(aP0, As[0] + wave * 512);
  GLD16(aP1, As[0] + (wave + 4) * 512);

  for (int kt = 0; kt < 16; ++kt) {
    const int p = kt & 1;
    __syncthreads();
    if (kt < 15) {
      const float* wsrc = w2e + (size_t)(kt + 1) * 32 * 1024;
      load_b8(wsrc, 1024, tid, fb);
      load_b8(wsrc, 1024, tid + 256, fb + 8);
      const int k = (kt + 1) * 32;
      GLD16(aP0 + k, As[1 - p] + wave * 512);
      GLD16(aP1 + k, As[1 - p] + (wave + 4) * 512);
    }
    bf16x8 af[4], bfr[4];
#pragma unroll
    for (int mi = 0; mi < 4; ++mi)
      af[mi] = *(const bf16x8*)(As[p] + (wr * 4 + mi) * 512 + lane * 8);
#pragma unroll
    for (int ni = 0; ni < 4; ++ni)
      bfr[ni] = *(const bf16x8*)(Bs[p] + (wc * 4 + ni) * 512 + lane * 8);
#pragma unroll
    for (int mi = 0; mi < 4; ++mi)
#pragma unroll
      for (int ni = 0; ni < 4; ++ni)
        acc[mi][ni] = __builtin_amdgcn_mfma_f32_16x16x32_bf16(af[mi], bfr[ni], acc[mi][ni], 0, 0, 0);
    if (kt < 15) {
      write_b8(fb, tid, Bs[1 - p]);
      write_b8(fb + 8, tid + 256, Bs[1 - p]);
    }
  }

  const int cl = lane & 15, ql = lane >> 4;
#pragma unroll
  for (int mi = 0; mi < 4; ++mi)
#pragma unroll
    for (int r = 0; r < 4; ++r) {
      const int slot = slotB + wr * 64 + mi * 16 + ql * 4 + r;
      const int tok = row_token[slot];
      if (tok < 0) continue;               // skip pads — no atomic storm
      const float p = row_scale[slot];
#pragma unroll
      for (int ni = 0; ni < 4; ++ni) {
        const int col = colBase + wc * 64 + ni * 16 + cl;
        float v = acc[mi][ni][r];
        if (ks == 0) v += p * w2b[e * 1024 + col];   // bias fold (once per token-expert)
        atomicAdd(out + (size_t)tok * 1024 + col, v);
      }
    }
}

extern "C" void kernel_launch(void* const* d_in, const int* in_sizes, int n_in,
                              void* d_out, int out_size, void* d_ws, size_t ws_size,
                              hipStream_t stream) {
  const float* x   = (const float*)d_in[0];   // (2048, 1024)
  const float* rw  = (const float*)d_in[1];   // (8, 1024)
  const float* rb  = (const float*)d_in[2];   // (8,)
  const float* w1  = (const float*)d_in[3];   // (8, 1024, 2048)
  const float* w1b = (const float*)d_in[4];   // (8, 2048)
  const float* w2  = (const float*)d_in[5];   // (8, 1024, 1024)
  const float* w2b = (const float*)d_in[6];   // (8, 1024)
  float* out = (float*)d_out;                 // 2048*1024
  float* ew  = out + (size_t)2048 * 1024;     // 2048*2

  char* ws = (char*)d_ws;
  u16* xb          = (u16*)(ws);                                 //  4 MiB
  u16* actS        = (u16*)(ws + (4ull << 20));                  // 32 MiB (8*2048 slots, 1024)
  int* row_token   = (int*)(ws + (36ull << 20));                 // 64 KiB (16384)
  float* row_scale = (float*)(ws + (36ull << 20) + (64 << 10));  // 64 KiB
  int* cnt         = (int*)(ws + (36ull << 20) + (128 << 10));   // 32 B

  hipMemsetAsync(out, 0, (size_t)2048 * 1024 * 4, stream);       // gemm2 accumulates
  hipMemsetAsync(row_token, 0xFF, 64 << 10, stream);             // pads = -1
  hipMemsetAsync(row_scale, 0, (64 << 10) + 32, stream);         // scales + cnt = 0
  prep_kernel<<<1536, 256, 0, stream>>>(x, rw, rb, xb, ew, row_token, row_scale, cnt);
  gemm1_act_kernel<<<2048, 256, 0, stream>>>(xb, w1, w1b, row_token, row_scale, cnt, actS);
  gemm2_add_kernel<<<2048, 256, 0, stream>>>(actS, w2, w2b, row_token, row_scale, cnt, out);
}